// Round 3
// baseline (295.119 us; speedup 1.0000x reference)
//
#include <hip/hip_runtime.h>

// Topo_Attention: out[b,c,t] = softmax_c( sum_l w[l]*tanh(sum_m v[l,m]*h_c[b,t,m]) )
// B=32, T=4096, M=256, L=128.  bf16 MFMA GEMM; memory(latency)-bound.
// R7: R6 minus the allocator-forced spill. R5/R6 both reported VGPR_Count=64 +
//     20-48MB of scratch WRITE traffic: with *dynamic* LDS the compiler can't
//     see the 64KB that caps occupancy at 2WG/CU (4 waves/EU), so regalloc
//     targeted 8 waves/EU (64-reg budget) and force-spilled ~30 live regs.
//     Fix: (a) static __shared__ V buffer (compiler sees the LDS bound),
//     (b) amdgpu_waves_per_eu(4,4) clamps the occupancy target -> 128-reg
//     budget, no spill. Structure unchanged from R6 (A direct global->reg,
//     depth-3 reg pipeline, sched_barrier(0) per step). Bit-identical numerics.

typedef unsigned short u16;
typedef unsigned int   u32;
typedef __bf16 bf16x8 __attribute__((ext_vector_type(8)));
typedef float  f32x4  __attribute__((ext_vector_type(4)));

union ABFrag { bf16x8 v; u16 u[8]; uint4 q4; };

__device__ __forceinline__ u16 f2bf(float f) {
  // round-to-nearest-even fp32 -> bf16 (finite inputs; no NaN path)
  u32 u = __float_as_uint(f);
  u += 0x7fffu + ((u >> 16) & 1u);
  return (u16)(u >> 16);
}

__device__ __forceinline__ float fast_tanh(float x) {
  float t = __builtin_amdgcn_exp2f(2.885390082f * x);
  return 1.0f - 2.0f * __builtin_amdgcn_rcpf(t + 1.0f);
}

#define NWG    1024
#define ITERS  2
#define TOT    (ITERS * 8)          // 16 ks-steps
#define ROWS_PER_IT (NWG * 64)      // 65536 t-rows per iter across the device

__global__ __launch_bounds__(512)
__attribute__((amdgpu_waves_per_eu(4, 4)))
void topo_attn_kernel(
    const float* __restrict__ h1, const float* __restrict__ h2,
    const float* __restrict__ w,  const float* __restrict__ vfp,
    float* __restrict__ out) {
  // Static 64KB so the compiler KNOWS occupancy is LDS-capped at 2 WG/CU.
  __shared__ __align__(16) u16 vlds[32768];   // V bf16, R1 rotate layout

  const int tid = threadIdx.x;

  { // one-time: convert V fp32 -> bf16 into LDS, rotate swizzle (chunk g -> (g+l)&31)
    const float4* src = (const float4*)vfp;
    #pragma unroll
    for (int k = 0; k < 8; ++k) {
      int gi = k * 512 + tid;            // 8-elem group index, 0..4095
      float4 f0 = src[gi * 2];
      float4 f1 = src[gi * 2 + 1];
      ABFrag t;
      t.u[0] = f2bf(f0.x); t.u[1] = f2bf(f0.y); t.u[2] = f2bf(f0.z); t.u[3] = f2bf(f0.w);
      t.u[4] = f2bf(f1.x); t.u[5] = f2bf(f1.y); t.u[6] = f2bf(f1.z); t.u[7] = f2bf(f1.w);
      int l = gi >> 5;                   // 0..127
      int g = gi & 31;                   // 0..31
      *(uint4*)&vlds[(l << 8) + (((g + l) & 31) << 3)] = t.q4;
    }
  }
  __syncthreads();                       // only barrier in the kernel

  const int lane = tid & 63;
  const int wave = tid >> 6;             // 0..7
  const int l15  = lane & 15;            // MFMA A-row / D-col lane index
  const int q    = lane >> 4;            // quad: A k = q*8+j ; D row = q*4+reg

  float wreg[8];
  #pragma unroll
  for (int lt = 0; lt < 8; ++lt) wreg[lt] = w[lt * 16 + l15];

  const int n0base = (blockIdx.x * 8 + wave) * 8;   // t-rows for it=0

  // Per-lane A source: A-row l15 (0-7 = h1 rows n0+l15, 8-15 = h2 rows n0+l15-8),
  // k-offset q*8 floats. Each lane's 32B fragment is contiguous in global memory;
  // each 128B line is fetched once and fully consumed by the 4 q-lanes of its row.
  const float* ap = (l15 < 8)
      ? h1 + (size_t)(n0base + l15) * 256
      : h2 + (size_t)(n0base + l15 - 8) * 256;
  ap += q * 8;

  // step s = it*8+ks: float offset = (s>>3)*ROWS_PER_IT*256 + (s&7)*32
  #define LDA(s, x, y) do {                                                       \
    const float* _p = ap + (size_t)((s) >> 3) * ((size_t)ROWS_PER_IT * 256)       \
                         + ((s) & 7) * 32;                                        \
    (x) = *(const float4*)_p; (y) = *(const float4*)(_p + 4); } while (0)

  // Depth-3 register pipeline; all pf indices compile-time (full unroll).
  float4 pf[4][2];
  LDA(0, pf[0][0], pf[0][1]);
  LDA(1, pf[1][0], pf[1][1]);
  LDA(2, pf[2][0], pf[2][1]);

  #pragma unroll
  for (int it = 0; it < ITERS; ++it) {
    f32x4 acc[8];
    #pragma unroll
    for (int lt = 0; lt < 8; ++lt) acc[lt] = (f32x4){0.f, 0.f, 0.f, 0.f};

    #pragma unroll
    for (int ks = 0; ks < 8; ++ks) {
      const int s = it * 8 + ks;
      // Pin the pipeline: nothing crosses a step boundary. Within the step the
      // scheduler is free (f2bf/MFMA/ds_read interleave).
      __builtin_amdgcn_sched_barrier(0);
      if (s + 3 < TOT) LDA(s + 3, pf[(s + 3) & 3][0], pf[(s + 3) & 3][1]);

      const float4 cfa = pf[s & 3][0];
      const float4 cfb = pf[s & 3][1];
      ABFrag a;                          // fp32 -> bf16 in-register
      a.u[0] = f2bf(cfa.x); a.u[1] = f2bf(cfa.y); a.u[2] = f2bf(cfa.z); a.u[3] = f2bf(cfa.w);
      a.u[4] = f2bf(cfb.x); a.u[5] = f2bf(cfb.y); a.u[6] = f2bf(cfb.z); a.u[7] = f2bf(cfb.w);

      #pragma unroll
      for (int lt = 0; lt < 8; ++lt) {
        const int l = (lt << 4) + l15;
        bf16x8 bfr = *(const bf16x8*)&vlds[(l << 8) + (((4 * ks + q + l) & 31) << 3)];
        acc[lt] = __builtin_amdgcn_mfma_f32_16x16x32_bf16(a.v, bfr, acc[lt], 0, 0, 0);
      }
    }

    // Epilogue: s_p[r] = sum_l w[l]*tanh(temp); D: col L=16*lt+l15, row m=q*4+r.
    // Rows m=0..7 are stream-0 (h1) scores, m=8..15 stream-1 (h2), same t-rows.
    float s_p[4] = {0.f, 0.f, 0.f, 0.f};
    #pragma unroll
    for (int lt = 0; lt < 8; ++lt) {
      #pragma unroll
      for (int r = 0; r < 4; ++r)
        s_p[r] += wreg[lt] * fast_tanh(acc[lt][r]);
    }
    #pragma unroll
    for (int r = 0; r < 4; ++r) {
      #pragma unroll
      for (int off = 1; off < 16; off <<= 1)
        s_p[r] += __shfl_xor(s_p[r], off);
    }
    const int r = l15 & 3;
    float sel = (r == 0) ? s_p[0] : (r == 1) ? s_p[1] : (r == 2) ? s_p[2] : s_p[3];
    float oth = __shfl_xor(sel, 32);     // partner quad carries the other stream
    if (q < 2 && l15 < 4) {
      int n = n0base + it * ROWS_PER_IT + q * 4 + l15;
      int b = n >> 12, t = n & 4095;
      float e  = __builtin_amdgcn_exp2f(-1.442695041f * (sel - oth));
      float a0 = __builtin_amdgcn_rcpf(1.0f + e);
      out[b * 8192 + t]        = a0;
      out[b * 8192 + 4096 + t] = 1.0f - a0;
    }
  }
}

extern "C" void kernel_launch(void* const* d_in, const int* in_sizes, int n_in,
                              void* d_out, int out_size, void* d_ws, size_t ws_size,
                              hipStream_t stream) {
  const float* h1 = (const float*)d_in[0];   // (32,4096,256) fp32
  const float* h2 = (const float*)d_in[1];   // (32,4096,256) fp32
  const float* w  = (const float*)d_in[2];   // (1,128) fp32
  const float* v  = (const float*)d_in[3];   // (128,256) fp32
  float* out = (float*)d_out;                // (32,2,4096) fp32

  topo_attn_kernel<<<NWG, 512, 0, stream>>>(h1, h2, w, v, out);
}

// Round 4
// 288.357 us; speedup vs baseline: 1.0235x; 1.0235x over previous
//
#include <hip/hip_runtime.h>

// Topo_Attention: out[b,c,t] = softmax_c( sum_l w[l]*tanh(sum_m v[l,m]*h_c[b,t,m]) )
// B=32, T=4096, M=256, L=128.  bf16 MFMA GEMM; memory(latency)-bound.
// R8: back to the R4 skeleton (global_load_lds staging -- the only structure that
//     compiles clean: R5-R7's A-in-reg variants all hit a 64-VGPR allocation +
//     20-50MB scratch spill). R4 was latency-bound (waves idle in s_waitcnt, 2.6
//     TB/s effective). Occupancy can't grow (V must be 64KB LDS per WG), so
//     double the ILP per wave instead: 2 t-tiles per wave per step (32 rows/it).
//     Per ks-step: stage 4KB, one fused vmcnt wait, two A-frags; each V fragment
//     is read once and feeds BOTH tiles' MFMAs (V LDS traffic + bank conflicts
//     halve per unit work). LDS 64KB V + 96KB A = 160KB (full pool; AITER fmha
//     precedent). vmcnt: 4 ops/step -> steady 8, tails 4/0. Numerics bit-identical.

typedef unsigned short u16;
typedef unsigned int   u32;
typedef __bf16 bf16x8 __attribute__((ext_vector_type(8)));
typedef float  f32x4  __attribute__((ext_vector_type(4)));

union ABFrag { bf16x8 v; u16 u[8]; uint4 q4; };

__device__ __forceinline__ u16 f2bf(float f) {
  // round-to-nearest-even fp32 -> bf16 (finite inputs; no NaN path)
  u32 u = __float_as_uint(f);
  u += 0x7fffu + ((u >> 16) & 1u);
  return (u16)(u >> 16);
}

__device__ __forceinline__ float fast_tanh(float x) {
  float t = __builtin_amdgcn_exp2f(2.885390082f * x);
  return 1.0f - 2.0f * __builtin_amdgcn_rcpf(t + 1.0f);
}

typedef const __attribute__((address_space(1))) void gvoid;
typedef __attribute__((address_space(3))) void lvoid;

__device__ __forceinline__ void dma16(const char* g, char* l) {
  __builtin_amdgcn_global_load_lds((gvoid*)g, (lvoid*)l, 16, 0, 0);
}

#define NWG    256
#define ITERS  4
#define TOT    (ITERS * 8)                 // 32 super-steps (each = 2 tiles)
#define ROWS_PER_IT (NWG * 8 * 16)         // 32768 t-rows per it
#define ITSTR  ((size_t)ROWS_PER_IT * 1024)
#define SMEMSZ (65536 + 8 * 3 * 4096)      // V 64KB + 8 waves x 3 slots x 4KB = 160KB

__global__ __launch_bounds__(512, 2) void topo_attn_kernel(
    const float* __restrict__ h1, const float* __restrict__ h2,
    const float* __restrict__ w,  const float* __restrict__ vfp,
    float* __restrict__ out) {
  extern __shared__ __align__(16) char smem[];
  u16*  vlds   = (u16*)smem;               // V bf16, R1 rotate layout (64KB)
  char* albase = smem + 65536;             // A staging (96KB)

  const int tid = threadIdx.x;

  { // one-time: convert V fp32 -> bf16 into LDS, rotate swizzle (chunk g -> (g+l)&31)
    const float4* src = (const float4*)vfp;
    #pragma unroll
    for (int k = 0; k < 8; ++k) {
      int gi = k * 512 + tid;            // 8-elem group index, 0..4095
      float4 f0 = src[gi * 2];
      float4 f1 = src[gi * 2 + 1];
      ABFrag t;
      t.u[0] = f2bf(f0.x); t.u[1] = f2bf(f0.y); t.u[2] = f2bf(f0.z); t.u[3] = f2bf(f0.w);
      t.u[4] = f2bf(f1.x); t.u[5] = f2bf(f1.y); t.u[6] = f2bf(f1.z); t.u[7] = f2bf(f1.w);
      int l = gi >> 5;                   // 0..127
      int g = gi & 31;                   // 0..31
      *(uint4*)&vlds[(l << 8) + (((g + l) & 31) << 3)] = t.q4;
    }
  }
  __syncthreads();                       // only barrier in the kernel

  const int lane = tid & 63;
  const int wave = tid >> 6;             // 0..7
  const int l15  = lane & 15;            // MFMA A-row / D-col lane index
  const int q    = lane >> 4;            // quad: A k = q*8+j ; D row = q*4+reg

  float wreg[8];
  #pragma unroll
  for (int lt = 0; lt < 8; ++lt) wreg[lt] = w[lt * 16 + l15];

  char* aslot = albase + wave * 12288;   // 3 slots x 4096B, wave-private

  // DMA source mapping: lane i deposits at slot + i*16 (HW-fixed). We want LDS
  // position (row r=i>>3, chunk j=i&7) to hold global chunk c=(j-r)&7 -> rotated
  // frag reads hit all 8 bank groups evenly. Same 128B lines, permuted lanes.
  const int rr = lane >> 3;              // row within 8-row block
  const int cc = lane & 7;               // dest chunk
  const int gchunk = (cc - rr) & 7;      // source chunk within the 128B k-slice

  const int n0base = (blockIdx.x * 8 + wave) * 16;  // 16 t-rows/wave for it=0
  const char* g1 = (const char*)h1 + (size_t)(n0base + rr) * 1024 + gchunk * 16;
  const char* g2 = (const char*)h2 + (size_t)(n0base + rr) * 1024 + gchunk * 16;

  // A-frag LDS read offsets (row r=l15&7, block=l15>>3, chunks 2q,2q+1 rotated):
  const int r7 = l15 & 7;
  const int fragbase = (l15 >> 3) * 1024 + r7 * 128;
  const int j1 = ((2 * q + r7) & 7) * 16;
  const int j2 = ((2 * q + 1 + r7) & 7) * 16;

  // Stage super-step s: tile0 = rows n0..n0+7 (h1+h2), tile1 = rows n0+8..n0+15.
  #define STAGE(s) do {                                                          \
    const size_t off = (size_t)((s) >> 3) * ITSTR + ((s) & 7) * 128;             \
    char* d = aslot + ((s) % 3) * 4096;                                          \
    dma16(g1 + off,        d);        dma16(g2 + off,        d + 1024);          \
    dma16(g1 + off + 8192, d + 2048); dma16(g2 + off + 8192, d + 3072);          \
  } while (0)

  STAGE(0);
  STAGE(1);

  #pragma unroll
  for (int it = 0; it < ITERS; ++it) {
    f32x4 acc0[8], acc1[8];
    #pragma unroll
    for (int lt = 0; lt < 8; ++lt) {
      acc0[lt] = (f32x4){0.f, 0.f, 0.f, 0.f};
      acc1[lt] = (f32x4){0.f, 0.f, 0.f, 0.f};
    }

    #pragma unroll
    for (int ks = 0; ks < 8; ++ks) {
      const int s = it * 8 + ks;
      // FIFO accounting (4 dma16/step): after issuing s+2, outstanding = 12;
      // step s's 4 ops done when <=8 remain. Tails: 4, then 0.
      if (s + 2 < TOT) {
        STAGE(s + 2);
        asm volatile("s_waitcnt vmcnt(8)" ::: "memory");
      } else if (s + 1 < TOT) {
        asm volatile("s_waitcnt vmcnt(4)" ::: "memory");
      } else {
        asm volatile("s_waitcnt vmcnt(0)" ::: "memory");
      }

      const char* ab = aslot + (s % 3) * 4096 + fragbase;
      float4 fa = *(const float4*)(ab + j1);          // tile0, k = q*8..q*8+3
      float4 fb = *(const float4*)(ab + j2);          // tile0, k = q*8+4..q*8+7
      float4 ga = *(const float4*)(ab + 2048 + j1);   // tile1
      float4 gb = *(const float4*)(ab + 2048 + j2);
      ABFrag a0, a1;
      a0.u[0] = f2bf(fa.x); a0.u[1] = f2bf(fa.y); a0.u[2] = f2bf(fa.z); a0.u[3] = f2bf(fa.w);
      a0.u[4] = f2bf(fb.x); a0.u[5] = f2bf(fb.y); a0.u[6] = f2bf(fb.z); a0.u[7] = f2bf(fb.w);
      a1.u[0] = f2bf(ga.x); a1.u[1] = f2bf(ga.y); a1.u[2] = f2bf(ga.z); a1.u[3] = f2bf(ga.w);
      a1.u[4] = f2bf(gb.x); a1.u[5] = f2bf(gb.y); a1.u[6] = f2bf(gb.z); a1.u[7] = f2bf(gb.w);

      #pragma unroll
      for (int lt = 0; lt < 8; ++lt) {
        const int l = (lt << 4) + l15;
        // One V fragment read feeds BOTH tiles (halves V LDS traffic vs R4).
        bf16x8 bfr = *(const bf16x8*)&vlds[(l << 8) + (((4 * ks + q + l) & 31) << 3)];
        acc0[lt] = __builtin_amdgcn_mfma_f32_16x16x32_bf16(a0.v, bfr, acc0[lt], 0, 0, 0);
        acc1[lt] = __builtin_amdgcn_mfma_f32_16x16x32_bf16(a1.v, bfr, acc1[lt], 0, 0, 0);
      }
    }

    // Epilogue per tile: s_p[r] = sum_l w[l]*tanh(temp); D: col L=16*lt+l15,
    // row m=q*4+r. Rows m=0..7 are h1 scores, m=8..15 h2 scores, same t-rows.
    #pragma unroll
    for (int tile = 0; tile < 2; ++tile) {           // unrolled -> static acc sel
      const f32x4* acc = tile ? acc1 : acc0;
      float s_p[4] = {0.f, 0.f, 0.f, 0.f};
      #pragma unroll
      for (int lt = 0; lt < 8; ++lt) {
        #pragma unroll
        for (int r = 0; r < 4; ++r)
          s_p[r] += wreg[lt] * fast_tanh(acc[lt][r]);
      }
      #pragma unroll
      for (int r = 0; r < 4; ++r) {
        #pragma unroll
        for (int off = 1; off < 16; off <<= 1)
          s_p[r] += __shfl_xor(s_p[r], off);
      }
      const int r = l15 & 3;
      float sel = (r == 0) ? s_p[0] : (r == 1) ? s_p[1] : (r == 2) ? s_p[2] : s_p[3];
      float oth = __shfl_xor(sel, 32);   // partner quad carries the other stream
      if (q < 2 && l15 < 4) {
        int n = n0base + it * ROWS_PER_IT + tile * 8 + q * 4 + l15;
        int b = n >> 12, t = n & 4095;
        float e  = __builtin_amdgcn_exp2f(-1.442695041f * (sel - oth));
        float a0v = __builtin_amdgcn_rcpf(1.0f + e);
        out[b * 8192 + t]        = a0v;
        out[b * 8192 + 4096 + t] = 1.0f - a0v;
      }
    }
  }
}

extern "C" void kernel_launch(void* const* d_in, const int* in_sizes, int n_in,
                              void* d_out, int out_size, void* d_ws, size_t ws_size,
                              hipStream_t stream) {
  const float* h1 = (const float*)d_in[0];   // (32,4096,256) fp32
  const float* h2 = (const float*)d_in[1];   // (32,4096,256) fp32
  const float* w  = (const float*)d_in[2];   // (1,128) fp32
  const float* v  = (const float*)d_in[3];   // (128,256) fp32
  float* out = (float*)d_out;                // (32,2,4096) fp32

  hipFuncSetAttribute((const void*)topo_attn_kernel,
                      hipFuncAttributeMaxDynamicSharedMemorySize, SMEMSZ);
  topo_attn_kernel<<<NWG, 512, SMEMSZ, stream>>>(h1, h2, w, v, out);
}